// Round 2
// baseline (633.078 us; speedup 1.0000x reference)
//
#include <hip/hip_runtime.h>

// APPNP block: 10 hops of symmetric-normalized propagation + FFN + residual.
// Round 10: agg path unchanged (R6 fused lockstep, ~38us/hop).
// BUILD REWRITTEN as two-phase binning: old 8-pass build_ell re-scanned dst
// 8x (FETCH 50MB) and its streaming reads evicted dirty ELL lines (WRITE
// 103MB for 21MB of logical output) -> 92us latency-bound. New: Phase A
// scans edges ONCE (int4 loads), packs (d_local | s<<14), appends to 8x64
// sub-streams via wave-aggregated ballot atomics (tails padded to 64B).
// Phase B is XCD-pinned scatter from the compact streams (no scan pollution
// -> ELL slice stays L2-resident, writes back once).
// FFN: weights now read via wave-uniform SCALAR loads from global (co =
// readfirstlane) instead of LDS b128 (removes the DS-pipe bottleneck: 288
// ds_read_b128/wave). LDS = only the 12.5KB h tile.

constexpr int N      = 100000;
constexpr int E      = 1600000;
constexpr int D      = 48;     // floats per node
constexpr int D4     = 12;     // float4 per node
constexpr int C8     = 6;      // chunks of 8 bf16 (16B) per node
constexpr int HALF   = N * C8 / 2;   // 300000 threads, 2 (n,c) pairs each
constexpr int NB     = 4;      // source buckets, width 25000
constexpr int BW     = 25000;  // bucket width (fits ushort local ids)
constexpr int BCAP   = 24;     // per-(node,bucket) cap; P(Bin(deg,1/4)>24) ~ 1e-8
constexpr int FNB    = 64;     // ffn nodes per block (256 thr = 64 nodes x 4 chunks)
constexpr int HP     = 49;     // padded LDS row stride (odd -> bank-conflict-free)
constexpr int NPART  = 8;      // dst partitions (one per XCD)
constexpr int PW     = 12500;  // partition width
constexpr int SUBS   = 64;     // sub-streams per partition
constexpr int SUBCAP = 4096;   // uints per sub-stream (mean 3136, sd ~52 -> 18 sd)
constexpr int TSTR   = 16;     // ints per tail slot (64B line -> no line contention)

typedef unsigned int uint;
typedef unsigned short ushort_t;
typedef uint  __attribute__((ext_vector_type(4))) nuint4;
typedef float __attribute__((ext_vector_type(4))) nfloat4;

__device__ __forceinline__ uint pack_bf16x2(float x, float y) {
    uint bx = __float_as_uint(x), by = __float_as_uint(y);
    bx = (bx + 0x7FFFu + ((bx >> 16) & 1u)) >> 16;          // RNE
    by = (by + 0x7FFFu + ((by >> 16) & 1u)) >> 16;
    return bx | (by << 16);
}

__device__ __forceinline__ void unpack_add(uint u, float& a0, float& a1) {
    a0 += __uint_as_float(u << 16);
    a1 += __uint_as_float(u & 0xFFFF0000u);
}

__global__ __launch_bounds__(256) void zero_kernel(int* __restrict__ cnt4,
                                                   int* __restrict__ tails) {
    int i = blockIdx.x * 256 + threadIdx.x;
    if (i < N * NB) cnt4[i] = 0;
    else if (i < N * NB + NPART * SUBS * TSTR) tails[i - N * NB] = 0;
}

// Phase A: single scan of the edge list. 4 edges/thread via int4. Each edge
// packed to one uint and appended to sub-stream (p, sub) with ONE global
// atomic per wave per partition (ballot aggregation). Group members write
// consecutive slots -> coalesced segments.
__global__ __launch_bounds__(256) void bin_scan_kernel(const int* __restrict__ src,
                                                       const int* __restrict__ dst,
                                                       uint* __restrict__ bins,
                                                       int* __restrict__ tails) {
    int t = blockIdx.x * 256 + threadIdx.x;
    int e0 = t * 4;
    if (e0 >= E) return;                       // E%1024==0 per-wave uniform
    int lane = threadIdx.x & 63;
    int sub = ((uint)t >> 6) & (SUBS - 1);     // wave-uniform stream id
    int4 dv = *(const int4*)(dst + e0);
    int4 sv = *(const int4*)(src + e0);
#pragma unroll
    for (int r = 0; r < 4; ++r) {
        int d = r == 0 ? dv.x : (r == 1 ? dv.y : (r == 2 ? dv.z : dv.w));
        int s = r == 0 ? sv.x : (r == 1 ? sv.y : (r == 2 ? sv.z : sv.w));
        uint p = (uint)d / (uint)PW;           // 0..7 (magic mul)
        uint pk = (uint)(d - (int)p * PW) | ((uint)s << 14);
#pragma unroll
        for (uint pp = 0; pp < NPART; ++pp) {
            unsigned long long m = __ballot(p == pp);
            if (m == 0ull) continue;           // wave-uniform
            int cnt = __popcll(m);
            int base = 0;
            if (lane == 0) base = atomicAdd(&tails[(pp * SUBS + sub) * TSTR], cnt);
            base = __shfl(base, 0);
            if (p == pp) {
                int before = __popcll(m & ((1ull << lane) - 1ull));
                int pos = base + before;
                if (pos < SUBCAP)
                    bins[((pp * SUBS + sub) << 12) + pos] = pk;
            }
        }
    }
}

// Phase B: XCD-pinned scatter. blockIdx&7 = partition -> cnt4 slice (200KB)
// and ELL slice (2.4MB) are L2-local and stay resident (no streaming scan).
// Grid 8x64x4: each block does a quarter of one sub-stream.
__global__ __launch_bounds__(256) void bin_scatter_kernel(const uint* __restrict__ bins,
                                                          const int* __restrict__ tails,
                                                          int* __restrict__ cnt4,
                                                          ushort_t* __restrict__ ell16) {
    int part = blockIdx.x & 7;
    int rest = blockIdx.x >> 3;       // 0..255
    int sub  = rest & (SUBS - 1);
    int q    = rest >> 6;             // 0..3 quarter
    int cnt = tails[(part * SUBS + sub) * TSTR];
    if (cnt > SUBCAP) cnt = SUBCAP;
    int i0 = q * (SUBCAP / 4);
    int i1 = min(cnt, (q + 1) * (SUBCAP / 4));
    const uint* bs = bins + ((part * SUBS + sub) << 12);
    int lo = part * PW;
    for (int i = i0 + threadIdx.x; i < i1; i += 256) {
        uint u = bs[i];
        int dl = u & 0x3FFF;
        int s  = (int)(u >> 14);
        int b = (s >= BW) + (s >= 2 * BW) + (s >= 3 * BW);
        int cidx = (lo + dl) * NB + b;
        int cpos = atomicAdd(&cnt4[cidx], 1);
        if (cpos < BCAP) ell16[(size_t)cidx * BCAP + cpos] = (ushort_t)(s - b * BW);
    }
}

// scaled0 = feat*norm (bf16, node-major 96B rows) and h0s = 0.1*feat (bf16).
// True in-degree = raw sum of the 4 bucket counters (cap only limits gathers).
__global__ __launch_bounds__(256) void norm_scaled0_kernel(const int* __restrict__ cnt4,
                                                           const float4* __restrict__ feat,
                                                           float* __restrict__ norm,
                                                           uint4* __restrict__ sA,
                                                           uint4* __restrict__ h0s) {
    int t = blockIdx.x * 256 + threadIdx.x;
    if (t >= N * C8) return;
    int n = t / C8;
    int c = t - n * C8;
    int4 cc = *(const int4*)(cnt4 + n * NB);
    float dg = (float)(cc.x + cc.y + cc.z + cc.w);
    float nm = 1.0f / sqrtf(fmaxf(dg, 1.0f));
    if (c == 0) norm[n] = nm;
    float4 v0 = feat[n * D4 + c * 2];
    float4 v1 = feat[n * D4 + c * 2 + 1];
    uint4 o;
    o.x = pack_bf16x2(v0.x * nm, v0.y * nm);
    o.y = pack_bf16x2(v0.z * nm, v0.w * nm);
    o.z = pack_bf16x2(v1.x * nm, v1.y * nm);
    o.w = pack_bf16x2(v1.z * nm, v1.w * nm);
    sA[t] = o;
    uint4 h;
    h.x = pack_bf16x2(v0.x * 0.1f, v0.y * 0.1f);
    h.y = pack_bf16x2(v0.z * 0.1f, v0.w * 0.1f);
    h.z = pack_bf16x2(v1.x * 0.1f, v1.y * 0.1f);
    h.w = pack_bf16x2(v1.z * 0.1f, v1.w * 0.1f);
    h0s[t] = h;
}

// Fused lockstep agg (R6): thread i owns (n0=i/6, c) and (n1=n0+50000, c).
// Bucket loop outermost; grid 1172 blocks = 4688 waves, fully co-resident.
// 6 consecutive lanes read one source node's contiguous 96B bf16 row.
template <bool LAST>
__global__ __launch_bounds__(256) void agg_kernel(const uint4* __restrict__ scaled_in,
                                                  const ushort_t* __restrict__ ell16,
                                                  const int* __restrict__ cnt4,
                                                  const float* __restrict__ norm,
                                                  const uint4* __restrict__ h0s,
                                                  uint4* __restrict__ scaled_out,
                                                  float4* __restrict__ h_out) {
    int i = blockIdx.x * 256 + threadIdx.x;
    if (i >= HALF) return;
    int n0 = i / C8;
    int c  = i - n0 * C8;
    int n1 = n0 + N / 2;
    int t0 = i, t1 = i + HALF;

    int4 cc0 = *(const int4*)(cnt4 + n0 * NB);
    int4 cc1 = *(const int4*)(cnt4 + n1 * NB);
    int cb0[NB] = {min(cc0.x, BCAP), min(cc0.y, BCAP), min(cc0.z, BCAP), min(cc0.w, BCAP)};
    int cb1[NB] = {min(cc1.x, BCAP), min(cc1.y, BCAP), min(cc1.z, BCAP), min(cc1.w, BCAP)};
    float nm0 = norm[n0], nm1 = norm[n1];
    const ushort_t* r0 = ell16 + (size_t)n0 * (NB * BCAP);
    const ushort_t* r1 = ell16 + (size_t)n1 * (NB * BCAP);

    float a0[8] = {0.f, 0.f, 0.f, 0.f, 0.f, 0.f, 0.f, 0.f};
    float a1[8] = {0.f, 0.f, 0.f, 0.f, 0.f, 0.f, 0.f, 0.f};

    auto addv = [](uint4 v, float* a) {
        unpack_add(v.x, a[0], a[1]); unpack_add(v.y, a[2], a[3]);
        unpack_add(v.z, a[4], a[5]); unpack_add(v.w, a[6], a[7]);
    };
    auto run = [&](const ushort_t* row, int cnt, const uint4* base, float* a) {
        int j = 0;
        for (; j + 4 <= cnt; j += 4) {
            int s0 = row[j], s1 = row[j + 1], s2 = row[j + 2], s3 = row[j + 3];
            uint4 v0 = base[s0 * C8];
            uint4 v1 = base[s1 * C8];
            uint4 v2 = base[s2 * C8];
            uint4 v3 = base[s3 * C8];
            addv(v0, a); addv(v1, a); addv(v2, a); addv(v3, a);
        }
        for (; j < cnt; ++j) {
            uint4 v = base[row[j] * C8];
            addv(v, a);
        }
    };

#pragma unroll
    for (int p = 0; p < NB; ++p) {
        const uint4* base = scaled_in + (size_t)p * (BW * C8) + c;
        run(r0 + p * BCAP, cb0[p], base, a0);
        run(r1 + p * BCAP, cb1[p], base, a1);
    }

    auto finish = [&](int t, int n, float nm, float* a) {
        nuint4 hs = __builtin_nontemporal_load((const nuint4*)&h0s[t]);
        float rr[8] = {0.f, 0.f, 0.f, 0.f, 0.f, 0.f, 0.f, 0.f};
        unpack_add(hs.x, rr[0], rr[1]); unpack_add(hs.y, rr[2], rr[3]);
        unpack_add(hs.z, rr[4], rr[5]); unpack_add(hs.w, rr[6], rr[7]);
        float s = 0.9f * nm;
        float hv[8];
#pragma unroll
        for (int k = 0; k < 8; ++k) hv[k] = fmaf(s, a[k], rr[k]);
        if (LAST) {
            nfloat4 o0 = {hv[0], hv[1], hv[2], hv[3]};
            nfloat4 o1 = {hv[4], hv[5], hv[6], hv[7]};
            __builtin_nontemporal_store(o0, (nfloat4*)&h_out[n * D4 + c * 2]);
            __builtin_nontemporal_store(o1, (nfloat4*)&h_out[n * D4 + c * 2 + 1]);
        } else {
            nuint4 o;
            o.x = pack_bf16x2(hv[0] * nm, hv[1] * nm);
            o.y = pack_bf16x2(hv[2] * nm, hv[3] * nm);
            o.z = pack_bf16x2(hv[4] * nm, hv[5] * nm);
            o.w = pack_bf16x2(hv[6] * nm, hv[7] * nm);
            __builtin_nontemporal_store(o, (nuint4*)&scaled_out[t]);
        }
    };
    finish(t0, n0, nm0, a0);
    finish(t1, n1, nm1, a1);
}

// rst = relu(h@w1 + b1)@w2 + b2 + features.
// 4 threads per node (chunk = tid>>6 owns 12 outputs), 64 nodes per block.
// h row staged in LDS stride 49 (free 2-way bank alias on scalar reads);
// hid reuses the same buffer between barriers. Weights/biases are read with
// wave-uniform SCALAR loads from global (co = readfirstlane, uniform control
// flow; only the final store is guarded) -> no DS-pipe cost for weights.
__global__ __launch_bounds__(256) void ffn_kernel(const float* __restrict__ r,
                                                  const float* __restrict__ feat,
                                                  const float* __restrict__ w1,
                                                  const float* __restrict__ b1,
                                                  const float* __restrict__ w2,
                                                  const float* __restrict__ b2,
                                                  float* __restrict__ rst) {
    __shared__ float sh[FNB * HP];      // h tile, reused for hid

    int tid = threadIdx.x;
    int nb = blockIdx.x * FNB;
    // stage h rows: up to 64 rows x 12 float4, coalesced global reads
    const float4* r4 = (const float4*)r + (size_t)nb * D4;
    int maxf4 = (N - nb) * D4;
    if (maxf4 > FNB * D4) maxf4 = FNB * D4;
    for (int f = tid; f < maxf4; f += 256) {
        float4 v = r4[f];
        int row = f / D4;
        int col = (f - row * D4) * 4;
        float* dp = sh + row * HP + col;
        dp[0] = v.x; dp[1] = v.y; dp[2] = v.z; dp[3] = v.w;
    }
    __syncthreads();

    int n_local = tid & 63;
    int co = __builtin_amdgcn_readfirstlane((tid >> 6) * 12);   // wave-uniform
    int node = nb + n_local;
    bool alive = node < N;
    const float* hrow = sh + n_local * HP;

    float acc[12];
#pragma unroll
    for (int j = 0; j < 12; ++j) acc[j] = b1[co + j];
#pragma unroll
    for (int k = 0; k < D; ++k) {
        float hk = hrow[k];
        const float4* wr = (const float4*)(w1 + k * D + co);
#pragma unroll
        for (int jc = 0; jc < 3; ++jc) {
            float4 wv = wr[jc];
            acc[4 * jc + 0] = fmaf(hk, wv.x, acc[4 * jc + 0]);
            acc[4 * jc + 1] = fmaf(hk, wv.y, acc[4 * jc + 1]);
            acc[4 * jc + 2] = fmaf(hk, wv.z, acc[4 * jc + 2]);
            acc[4 * jc + 3] = fmaf(hk, wv.w, acc[4 * jc + 3]);
        }
    }
#pragma unroll
    for (int j = 0; j < 12; ++j) acc[j] = fmaxf(acc[j], 0.0f);
    __syncthreads();                    // everyone done reading h tile
    {
        float* hw = sh + n_local * HP + co;
#pragma unroll
        for (int j = 0; j < 12; ++j) hw[j] = acc[j];
    }
    __syncthreads();                    // hid tile ready
#pragma unroll
    for (int j = 0; j < 12; ++j) acc[j] = b2[co + j];
#pragma unroll
    for (int k = 0; k < D; ++k) {
        float hk = hrow[k];
        const float4* wr = (const float4*)(w2 + k * D + co);
#pragma unroll
        for (int jc = 0; jc < 3; ++jc) {
            float4 wv = wr[jc];
            acc[4 * jc + 0] = fmaf(hk, wv.x, acc[4 * jc + 0]);
            acc[4 * jc + 1] = fmaf(hk, wv.y, acc[4 * jc + 1]);
            acc[4 * jc + 2] = fmaf(hk, wv.z, acc[4 * jc + 2]);
            acc[4 * jc + 3] = fmaf(hk, wv.w, acc[4 * jc + 3]);
        }
    }
    if (alive) {
        const float4* f4 = (const float4*)feat + (size_t)node * D4 + (co / 4);
        float4*       o4 = (float4*)rst + (size_t)node * D4 + (co / 4);
#pragma unroll
        for (int jc = 0; jc < 3; ++jc) {
            float4 fv = f4[jc];
            float4 o;
            o.x = acc[4 * jc + 0] + fv.x;
            o.y = acc[4 * jc + 1] + fv.y;
            o.z = acc[4 * jc + 2] + fv.z;
            o.w = acc[4 * jc + 3] + fv.w;
            o4[jc] = o;
        }
    }
}

extern "C" void kernel_launch(void* const* d_in, const int* in_sizes, int n_in,
                              void* d_out, int out_size, void* d_ws, size_t ws_size,
                              hipStream_t stream) {
    const float* feat = (const float*)d_in[0];
    const int*   src  = (const int*)d_in[1];
    const int*   dst  = (const int*)d_in[2];
    const float* w1   = (const float*)d_in[3];
    const float* b1   = (const float*)d_in[4];
    const float* w2   = (const float*)d_in[5];
    const float* b2   = (const float*)d_in[6];

    float* rst   = (float*)d_out;                  // output 0: [N, D]
    float* r_out = rst + (size_t)N * D;            // output 1: [N, D]

    // workspace layout (16B-aligned offsets)
    char*     w     = (char*)d_ws;
    int*      cnt4  = (int*)w;                               //  1,600,000 B
    float*    norm  = (float*)(w + 1600000);                 //    400,000 B
    ushort_t* ell16 = (ushort_t*)(w + 2000000);              // 19,200,000 B
    uint4*    sA    = (uint4*)(w + 2000000 + 19200000);      //  9,600,000 B
    uint4*    sB    = sA + (size_t)N * C8;                   //  9,600,000 B
    uint4*    h0s   = sB + (size_t)N * C8;                   //  9,600,000 B
    // build-phase scratch, dead before sA/sB are first written:
    uint*     bins  = (uint*)sA;                             //  8,388,608 B (aliases sA)
    int*      tails = (int*)sB;                              //     32,768 B (aliases sB)

    zero_kernel<<<(N * NB + NPART * SUBS * TSTR + 255) / 256, 256, 0, stream>>>(cnt4, tails);
    bin_scan_kernel<<<(E / 4 + 255) / 256, 256, 0, stream>>>(src, dst, bins, tails);
    bin_scatter_kernel<<<NPART * SUBS * 4, 256, 0, stream>>>(bins, tails, cnt4, ell16);
    norm_scaled0_kernel<<<(N * C8 + 255) / 256, 256, 0, stream>>>(
        cnt4, (const float4*)feat, norm, sA, h0s);

    uint4* bufs[2] = {sA, sB};
    for (int hop = 0; hop < 10; ++hop) {
        const uint4* in  = bufs[hop & 1];
        uint4*       out = bufs[(hop + 1) & 1];
        if (hop < 9) {
            agg_kernel<false><<<(HALF + 255) / 256, 256, 0, stream>>>(
                in, ell16, cnt4, norm, h0s, out, nullptr);
        } else {
            agg_kernel<true><<<(HALF + 255) / 256, 256, 0, stream>>>(
                in, ell16, cnt4, norm, h0s, nullptr, (float4*)r_out);
        }
    }

    ffn_kernel<<<(N + FNB - 1) / FNB, 256, 0, stream>>>(
        r_out, feat, w1, b1, w2, b2, rst);
}